// Round 14
// baseline (127.821 us; speedup 1.0000x reference)
//
#include <hip/hip_runtime.h>
#include <stdint.h>

#define B_ 2
#define T_ 2048
#define C_ 1024
#define H_ 16
#define D_ 64
#define M_ (B_*T_)
#define BHTD_ (B_*H_*T_*D_)

typedef __bf16 bf16x8 __attribute__((ext_vector_type(8)));
typedef __bf16 bf16x4 __attribute__((ext_vector_type(4)));
typedef __bf16 bf16x2 __attribute__((ext_vector_type(2)));
typedef float f32x4 __attribute__((ext_vector_type(4)));
typedef float f32x16 __attribute__((ext_vector_type(16)));

static __device__ __forceinline__ unsigned short f32_bf16(float f) {
    unsigned int u = __float_as_uint(f);
    u += 0x7FFFu + ((u >> 16) & 1u);   // round-to-nearest-even
    return (unsigned short)(u >> 16);
}

static __device__ __forceinline__ int pack_bf16_2(float a, float b) {
    bf16x2 v = {(__bf16)a, (__bf16)b};
    return __builtin_bit_cast(int, v);
}

// ---------------- fused prep: cast x + transpose both W (one launch) ----------------
__global__ void prep_kernel(const float* __restrict__ x, unsigned short* __restrict__ xbf,
                            const float* __restrict__ Wqkv, unsigned short* __restrict__ wqkv_t,
                            const float* __restrict__ Wproj, unsigned short* __restrict__ wproj_t) {
    __shared__ float tile[32][33];
    const int id = blockIdx.x;
    const int tid = threadIdx.x;
    if (id < 4096) {
        int i = (id * 256 + tid) * 4;
        float4 f = *(const float4*)(x + i);
        ushort4 o;
        o.x = f32_bf16(f.x); o.y = f32_bf16(f.y); o.z = f32_bf16(f.z); o.w = f32_bf16(f.w);
        *(ushort4*)(xbf + i) = o;
        return;
    }
    const float* W; unsigned short* Wt; int K, N, bx, by;
    if (id < 7168) {
        int r = id - 4096; W = Wqkv; Wt = wqkv_t; K = 1024; N = 3072;
        bx = r % 96; by = r / 96;
    } else {
        int r = id - 7168; W = Wproj; Wt = wproj_t; K = 1024; N = 1024;
        bx = r & 31; by = r >> 5;
    }
    int n0 = bx * 32, k0 = by * 32;
    int tx = tid & 31, ty = tid >> 5;
    #pragma unroll
    for (int j = 0; j < 32; j += 8)
        tile[ty + j][tx] = W[(size_t)(k0 + ty + j) * N + n0 + tx];
    __syncthreads();
    #pragma unroll
    for (int j = 0; j < 32; j += 8)
        Wt[(size_t)(n0 + ty + j) * K + k0 + tx] = f32_bf16(tile[tx][ty + j]);
}

// ---------------- GEMM: 2-phase dbuf gll staging; tile 128 x BN ----------------
template<int EPI, int BN>
__global__ __launch_bounds__(256) void gemm_bt(
    const unsigned short* __restrict__ A,
    const unsigned short* __restrict__ Bt,
    const float* __restrict__ bias,
    unsigned short* __restrict__ out_bf16,
    float* __restrict__ out_f32,
    int M, int N, int K)
{
    constexpr int NI = (BN == 128) ? 4 : 2;
    constexpr int BSTR = BN * 32;
    __shared__ __align__(16) unsigned short smem[16640];
    unsigned short* AsU = smem;
    unsigned short* BsU = smem + 8192;
    int tid = threadIdx.x;
    int lane = tid & 63, wid = tid >> 6;
    int fr = lane & 15, fg = lane >> 4;
    int row0 = blockIdx.x * 128, col0 = blockIdx.y * BN;
    int wm = (wid >> 1) * 64, wn = (wid & 1) * (BN / 2);

    f32x4 acc[4][NI];
    #pragma unroll
    for (int i = 0; i < 4; ++i)
        #pragma unroll
        for (int j = 0; j < NI; ++j)
            acc[i][j] = (f32x4){0.f, 0.f, 0.f, 0.f};

    const int srw = lane >> 2;
    const int scl = (lane & 3) * 8;
    const int c0 = wid * 2, c1 = wid * 2 + 1;

    auto stage = [&](int buf, int k0) {
        __builtin_amdgcn_global_load_lds(
            (const __attribute__((address_space(1))) void*)(A + (size_t)(row0 + c0 * 16 + srw) * K + k0 + scl),
            (__attribute__((address_space(3))) void*)(AsU + buf * 4096 + c0 * 512), 16, 0, 0);
        __builtin_amdgcn_global_load_lds(
            (const __attribute__((address_space(1))) void*)(A + (size_t)(row0 + c1 * 16 + srw) * K + k0 + scl),
            (__attribute__((address_space(3))) void*)(AsU + buf * 4096 + c1 * 512), 16, 0, 0);
        if (BN == 128) {
            __builtin_amdgcn_global_load_lds(
                (const __attribute__((address_space(1))) void*)(Bt + (size_t)(col0 + c0 * 16 + srw) * K + k0 + scl),
                (__attribute__((address_space(3))) void*)(BsU + buf * BSTR + c0 * 512), 16, 0, 0);
            __builtin_amdgcn_global_load_lds(
                (const __attribute__((address_space(1))) void*)(Bt + (size_t)(col0 + c1 * 16 + srw) * K + k0 + scl),
                (__attribute__((address_space(3))) void*)(BsU + buf * BSTR + c1 * 512), 16, 0, 0);
        } else {
            __builtin_amdgcn_global_load_lds(
                (const __attribute__((address_space(1))) void*)(Bt + (size_t)(col0 + wid * 16 + srw) * K + k0 + scl),
                (__attribute__((address_space(3))) void*)(BsU + buf * BSTR + wid * 512), 16, 0, 0);
        }
    };

    stage(0, 0);
    __syncthreads();

    int cur = 0;
    for (int k0 = 0; k0 < K; k0 += 32) {
        if (k0 + 32 < K) stage(cur ^ 1, k0 + 32);

        bf16x8 af[4], bfr[NI];
        #pragma unroll
        for (int i = 0; i < 4; ++i)
            af[i] = *(const bf16x8*)(AsU + cur * 4096 + (wm + i * 16 + fr) * 32 + fg * 8);
        #pragma unroll
        for (int i = 0; i < NI; ++i)
            bfr[i] = *(const bf16x8*)(BsU + cur * BSTR + (wn + i * 16 + fr) * 32 + fg * 8);
        #pragma unroll
        for (int mi = 0; mi < 4; ++mi)
            #pragma unroll
            for (int ni = 0; ni < NI; ++ni)
                acc[mi][ni] = __builtin_amdgcn_mfma_f32_16x16x32_bf16(af[mi], bfr[ni], acc[mi][ni], 0, 0, 0);

        __syncthreads();
        cur ^= 1;
    }

    if (EPI == 0 && BN == 128 && col0 >= 2048) {
        // V blocks: transpose through LDS, coalesced [d][T] stores
        #pragma unroll
        for (int ni = 0; ni < NI; ++ni) {
            const int cl = wn + ni * 16 + fr;
            const float bv = bias[col0 + cl];
            #pragma unroll
            for (int mi = 0; mi < 4; ++mi) {
                const int rl = wm + mi * 16 + fg * 4;
                bf16x4 pk = {(__bf16)(acc[mi][ni][0] + bv), (__bf16)(acc[mi][ni][1] + bv),
                             (__bf16)(acc[mi][ni][2] + bv), (__bf16)(acc[mi][ni][3] + bv)};
                uint2 w = __builtin_bit_cast(uint2, pk);
                *(unsigned int*)(smem + cl * 130 + rl)     = w.x;
                *(unsigned int*)(smem + cl * 130 + rl + 2) = w.y;
            }
        }
        __syncthreads();
        const int c = tid >> 1, half = tid & 1;
        const int col = col0 + c;
        const int d = col & 63, h2 = (col >> 6) & 15;
        const int bb = row0 >> 11;
        const int t0 = (row0 & 2047) + half * 64;
        unsigned short* dst = out_bf16 + (size_t)2 * BHTD_ +
                              ((size_t)(bb * H_ + h2) * D_ + d) * T_ + t0;
        const unsigned short* src = smem + c * 130 + half * 64;
        #pragma unroll
        for (int j = 0; j < 8; ++j) {
            uint4 v;
            v.x = *(const unsigned int*)(src + j * 8 + 0);
            v.y = *(const unsigned int*)(src + j * 8 + 2);
            v.z = *(const unsigned int*)(src + j * 8 + 4);
            v.w = *(const unsigned int*)(src + j * 8 + 6);
            *(uint4*)(dst + j * 8) = v;
        }
        return;
    }

    #pragma unroll
    for (int mi = 0; mi < 4; ++mi) {
        int rowb = row0 + wm + mi * 16 + fg * 4;
        #pragma unroll
        for (int ni = 0; ni < NI; ++ni) {
            int col = col0 + wn + ni * 16 + fr;
            float bv = bias[col];
            #pragma unroll
            for (int r = 0; r < 4; ++r) {
                float v = acc[mi][ni][r] + bv;
                int rr = rowb + r;
                if (EPI == 0) {
                    int part = col >> 10, c = col & 1023;
                    int h = c >> 6, d = c & 63;
                    int b = rr >> 11, t = rr & 2047;
                    if (part == 0) v *= 0.18033688011112042f;   // fold log2(e)/sqrt(D) into Q
                    size_t idx = (size_t)part * BHTD_ + ((size_t)(b * H_ + h) * T_ + t) * D_ + d;
                    out_bf16[idx] = f32_bf16(v);
                } else {
                    out_f32[(size_t)rr * N + col] = v;
                }
            }
        }
    }
}

// ---------------- causal flash attention v11: dual-chunk x 32x32 in-register P ----------------
// 512 blocks x 128 threads (2 waves). Wave = 32 rows of hi chunk (31-iq) AND 32
// rows of lo chunk (iq), sharing each KV tile's K/V frags. Every block = 33
// stream-tile units (balanced). S^T = mfma_32x32x16(K,Q) per stream; P stays
// in registers (pack_bf16 + permlane32_swap, verified v9); NO P LDS.
// K/V^T staged via global_load_lds (inverse-swizzled source), double-buffered.
__global__ __launch_bounds__(128, 1) void attn_kernel(
    const unsigned short* __restrict__ qg,
    const unsigned short* __restrict__ kg,
    const unsigned short* __restrict__ vtg,  // [bh][D][T]
    unsigned short* __restrict__ y)
{
    const int id = blockIdx.x;
    const int xcd = id & 7, loc = id >> 3;
    const int bh = xcd * 4 + (loc & 3);      // 4 heads per XCD -> K/V L2-resident
    const int iq = loc >> 2;                 // [0,16)
    const int chhi = 31 - iq, chlo = iq;
    const int b = bh >> 4, h = bh & 15;
    const int tid = threadIdx.x, wid = tid >> 6, lane = tid & 63;
    const int lq = lane & 31, hi = lane >> 5;

    const unsigned short* qp = qg + (size_t)bh * (T_ * D_);
    const char* kpB = (const char*)(kg + (size_t)bh * (T_ * D_));
    const char* vpB = (const char*)(vtg + (size_t)bh * (D_ * T_));

    __shared__ __align__(16) char Ks[2][8192];   // [kv][d] bf16, 128B rows, swizzled
    __shared__ __align__(16) char Vs[2][8192];   // [d][kv] bf16, 128B rows, swizzled

    const int rhi = chhi * 64 + wid * 32;
    const int rlo = chlo * 64 + wid * 32;
    const int ntk = chhi + 1, ntlo = chlo + 1;

    // Q fragments (pre-scaled by log2e/sqrt(D)): B-operand of mfma(K,Q)
    bf16x8 qh[4], ql[4];
    #pragma unroll
    for (int ds = 0; ds < 4; ++ds) {
        qh[ds] = *(const bf16x8*)(qp + (size_t)(rhi + lq) * D_ + ds * 16 + hi * 8);
        ql[ds] = *(const bf16x8*)(qp + (size_t)(rlo + lq) * D_ + ds * 16 + hi * 8);
    }

    f32x16 oh0, oh1, ol0, ol1;
    #pragma unroll
    for (int e = 0; e < 16; ++e) { oh0[e] = 0.f; oh1[e] = 0.f; ol0[e] = 0.f; ol1[e] = 0.f; }
    float lh = 0.f, ll = 0.f;

    // staging (2 waves x 4 chunks of 8 rows each for K and V)
    const int srow8 = lane >> 3;
    const int scol  = (lane & 7) * 16;
    const int ssw   = srow8 << 4;

    auto stage = [&](int buf, int kv0) {
        #pragma unroll
        for (int blk = 0; blk < 4; ++blk) {
            const int rbase = wid * 32 + blk * 8;
            __builtin_amdgcn_global_load_lds(
                (const __attribute__((address_space(1))) void*)
                    (kpB + (size_t)(kv0 + rbase + srow8) * 128 + (scol ^ ssw)),
                (__attribute__((address_space(3))) void*)(Ks[buf] + rbase * 128), 16, 0, 0);
            __builtin_amdgcn_global_load_lds(
                (const __attribute__((address_space(1))) void*)
                    (vpB + (size_t)(rbase + srow8) * 4096 + kv0 * 2 + (scol ^ ssw)),
                (__attribute__((address_space(3))) void*)(Vs[buf] + rbase * 128), 16, 0, 0);
        }
    };

    // P -> PV B-frag: 4 packs + 2 permlane32_swap per 16-kv step (verified v9)
    auto make_pb = [&](const f32x16& p4, int g4a) -> bf16x8 {
        int A0 = pack_bf16_2(p4[g4a * 4 + 0], p4[g4a * 4 + 1]);
        int A1 = pack_bf16_2(p4[g4a * 4 + 2], p4[g4a * 4 + 3]);
        int B0 = pack_bf16_2(p4[g4a * 4 + 4], p4[g4a * 4 + 5]);
        int B1 = pack_bf16_2(p4[g4a * 4 + 6], p4[g4a * 4 + 7]);
        auto ra = __builtin_amdgcn_permlane32_swap(A0, B0, false, false);
        auto rb = __builtin_amdgcn_permlane32_swap(A1, B1, false, false);
        int4 w;
        w.x = ra[0]; w.y = rb[0]; w.z = ra[1]; w.w = rb[1];
        return __builtin_bit_cast(bf16x8, w);
    };

    stage(0, 0);
    __syncthreads();

    const int lsw = (lq & 7) << 4;
    int cur = 0;
    for (int t = 0; t < ntk; ++t) {
        const int kv0 = t * 64;
        if (t + 1 < ntk) stage(cur ^ 1, kv0 + 64);   // prefetch under compute

        const char* Kb = Ks[cur];
        const char* Vb = Vs[cur];
        const bool lo_act = (t < ntlo);               // wave-uniform

        // ---- S^T = mfma(K, Q): K frags read ONCE, feed both streams ----
        f32x16 sh0, sh1, sl0, sl1;
        #pragma unroll
        for (int e = 0; e < 16; ++e) { sh0[e] = 0.f; sh1[e] = 0.f; sl0[e] = 0.f; sl1[e] = 0.f; }
        #pragma unroll
        for (int ds = 0; ds < 4; ++ds) {
            bf16x8 kfA = *(const bf16x8*)(Kb + lq * 128        + ((ds * 32 + hi * 16) ^ lsw));
            bf16x8 kfB = *(const bf16x8*)(Kb + (32 + lq) * 128 + ((ds * 32 + hi * 16) ^ lsw));
            sh0 = __builtin_amdgcn_mfma_f32_32x32x16_bf16(kfA, qh[ds], sh0, 0, 0, 0);
            sh1 = __builtin_amdgcn_mfma_f32_32x32x16_bf16(kfB, qh[ds], sh1, 0, 0, 0);
            if (lo_act) {
                sl0 = __builtin_amdgcn_mfma_f32_32x32x16_bf16(kfA, ql[ds], sl0, 0, 0, 0);
                sl1 = __builtin_amdgcn_mfma_f32_32x32x16_bf16(kfB, ql[ds], sl1, 0, 0, 0);
            }
        }

        // ---- V^T A-frags read ONCE, shared by both streams ----
        bf16x8 vf[2][4];
        #pragma unroll
        for (int dd = 0; dd < 2; ++dd)
            #pragma unroll
            for (int st = 0; st < 4; ++st)
                vf[dd][st] = *(const bf16x8*)(Vb + (dd * 32 + lq) * 128 +
                                              ((st * 32 + hi * 16) ^ lsw));

        // ---- hi stream: no-max softmax + in-register PV ----
        {
            const bool diag = (t == chhi);
            const int qrow = rhi + lq;
            if (diag) {
                #pragma unroll
                for (int e = 0; e < 16; ++e) {
                    const int kvl = (e & 3) + ((e >> 2) << 3) + hi * 4;
                    sh0[e] = exp2f((kv0 + kvl <= qrow) ? sh0[e] : -1e30f);
                    sh1[e] = exp2f((kv0 + 32 + kvl <= qrow) ? sh1[e] : -1e30f);
                }
            } else {
                #pragma unroll
                for (int e = 0; e < 16; ++e) { sh0[e] = exp2f(sh0[e]); sh1[e] = exp2f(sh1[e]); }
            }
            float a0 = 0.f;
            #pragma unroll
            for (int e = 0; e < 16; ++e) a0 += sh0[e] + sh1[e];
            lh += a0;
            bf16x8 pb = make_pb(sh0, 0);
            oh0 = __builtin_amdgcn_mfma_f32_32x32x16_bf16(vf[0][0], pb, oh0, 0, 0, 0);
            oh1 = __builtin_amdgcn_mfma_f32_32x32x16_bf16(vf[1][0], pb, oh1, 0, 0, 0);
            pb = make_pb(sh0, 2);
            oh0 = __builtin_amdgcn_mfma_f32_32x32x16_bf16(vf[0][1], pb, oh0, 0, 0, 0);
            oh1 = __builtin_amdgcn_mfma_f32_32x32x16_bf16(vf[1][1], pb, oh1, 0, 0, 0);
            pb = make_pb(sh1, 0);
            oh0 = __builtin_amdgcn_mfma_f32_32x32x16_bf16(vf[0][2], pb, oh0, 0, 0, 0);
            oh1 = __builtin_amdgcn_mfma_f32_32x32x16_bf16(vf[1][2], pb, oh1, 0, 0, 0);
            pb = make_pb(sh1, 2);
            oh0 = __builtin_amdgcn_mfma_f32_32x32x16_bf16(vf[0][3], pb, oh0, 0, 0, 0);
            oh1 = __builtin_amdgcn_mfma_f32_32x32x16_bf16(vf[1][3], pb, oh1, 0, 0, 0);
        }
        // ---- lo stream ----
        if (lo_act) {
            const bool diag = (t == chlo);
            const int qrow = rlo + lq;
            if (diag) {
                #pragma unroll
                for (int e = 0; e < 16; ++e) {
                    const int kvl = (e & 3) + ((e >> 2) << 3) + hi * 4;
                    sl0[e] = exp2f((kv0 + kvl <= qrow) ? sl0[e] : -1e30f);
                    sl1[e] = exp2f((kv0 + 32 + kvl <= qrow) ? sl1[e] : -1e30f);
                }
            } else {
                #pragma unroll
                for (int e = 0; e < 16; ++e) { sl0[e] = exp2f(sl0[e]); sl1[e] = exp2f(sl1[e]); }
            }
            float a0 = 0.f;
            #pragma unroll
            for (int e = 0; e < 16; ++e) a0 += sl0[e] + sl1[e];
            ll += a0;
            bf16x8 pb = make_pb(sl0, 0);
            ol0 = __builtin_amdgcn_mfma_f32_32x32x16_bf16(vf[0][0], pb, ol0, 0, 0, 0);
            ol1 = __builtin_amdgcn_mfma_f32_32x32x16_bf16(vf[1][0], pb, ol1, 0, 0, 0);
            pb = make_pb(sl0, 2);
            ol0 = __builtin_amdgcn_mfma_f32_32x32x16_bf16(vf[0][1], pb, ol0, 0, 0, 0);
            ol1 = __builtin_amdgcn_mfma_f32_32x32x16_bf16(vf[1][1], pb, ol1, 0, 0, 0);
            pb = make_pb(sl1, 0);
            ol0 = __builtin_amdgcn_mfma_f32_32x32x16_bf16(vf[0][2], pb, ol0, 0, 0, 0);
            ol1 = __builtin_amdgcn_mfma_f32_32x32x16_bf16(vf[1][2], pb, ol1, 0, 0, 0);
            pb = make_pb(sl1, 2);
            ol0 = __builtin_amdgcn_mfma_f32_32x32x16_bf16(vf[0][3], pb, ol0, 0, 0, 0);
            ol1 = __builtin_amdgcn_mfma_f32_32x32x16_bf16(vf[1][3], pb, ol1, 0, 0, 0);
        }

        __syncthreads();   // drains prefetch gll; all waves done with cur buffer
        cur ^= 1;
    }

    // ---- epilogue: per stream, reduce l across hi halves, normalize, store ----
    #pragma unroll
    for (int s = 0; s < 2; ++s) {
        float lr = s ? ll : lh;
        lr += __shfl_xor(lr, 32);
        const float inv = 1.f / lr;
        const int trow = (s ? rlo : rhi) + lq;
        unsigned short* yrow = y + ((size_t)b * T_ + trow) * C_ + h * 64;
        #pragma unroll
        for (int dd = 0; dd < 2; ++dd) {
            const f32x16& o = s ? (dd ? ol1 : ol0) : (dd ? oh1 : oh0);
            #pragma unroll
            for (int g4 = 0; g4 < 4; ++g4) {
                bf16x4 ov = {(__bf16)(o[g4 * 4 + 0] * inv), (__bf16)(o[g4 * 4 + 1] * inv),
                             (__bf16)(o[g4 * 4 + 2] * inv), (__bf16)(o[g4 * 4 + 3] * inv)};
                *(uint2*)(yrow + dd * 32 + g4 * 8 + hi * 4) = __builtin_bit_cast(uint2, ov);
            }
        }
    }
}

// ---------------- launch ----------------
extern "C" void kernel_launch(void* const* d_in, const int* in_sizes, int n_in,
                              void* d_out, int out_size, void* d_ws, size_t ws_size,
                              hipStream_t stream) {
    const float* x     = (const float*)d_in[0];
    const float* Wqkv  = (const float*)d_in[1];
    const float* bqkv  = (const float*)d_in[2];
    const float* Wproj = (const float*)d_in[3];
    const float* bproj = (const float*)d_in[4];
    float* out = (float*)d_out;

    char* ws = (char*)d_ws;
    unsigned short* x_bf    = (unsigned short*)(ws);                 //  8 MB
    unsigned short* wqkv_t  = (unsigned short*)(ws + 8388608);       //  6 MB
    unsigned short* wproj_t = (unsigned short*)(ws + 14680064);      //  2 MB
    unsigned short* qkv     = (unsigned short*)(ws + 16777216);      // 24 MB
    unsigned short* ybuf    = (unsigned short*)(ws + 41943040);      //  8 MB

    prep_kernel<<<dim3(8192), 256, 0, stream>>>(x, x_bf, Wqkv, wqkv_t, Wproj, wproj_t);

    gemm_bt<0, 128><<<dim3(M_ / 128, 3072 / 128), 256, 0, stream>>>(
        x_bf, wqkv_t, bqkv, qkv, nullptr, M_, 3072, 1024);

    attn_kernel<<<dim3(512), 128, 0, stream>>>(
        qkv, qkv + (size_t)BHTD_, qkv + 2 * (size_t)BHTD_, ybuf);

    gemm_bt<1, 64><<<dim3(M_ / 128, 1024 / 64), 256, 0, stream>>>(
        ybuf, wproj_t, bproj, nullptr, out, M_, 1024, 1024);
}

// Round 15
// 120.407 us; speedup vs baseline: 1.0616x; 1.0616x over previous
//
#include <hip/hip_runtime.h>
#include <stdint.h>

#define B_ 2
#define T_ 2048
#define C_ 1024
#define H_ 16
#define D_ 64
#define M_ (B_*T_)
#define BHTD_ (B_*H_*T_*D_)

typedef __bf16 bf16x8 __attribute__((ext_vector_type(8)));
typedef __bf16 bf16x4 __attribute__((ext_vector_type(4)));
typedef float f32x4 __attribute__((ext_vector_type(4)));

static __device__ __forceinline__ unsigned short f32_bf16(float f) {
    unsigned int u = __float_as_uint(f);
    u += 0x7FFFu + ((u >> 16) & 1u);   // round-to-nearest-even
    return (unsigned short)(u >> 16);
}

// ---------------- fused prep: cast x + transpose both W (one launch) ----------------
__global__ void prep_kernel(const float* __restrict__ x, unsigned short* __restrict__ xbf,
                            const float* __restrict__ Wqkv, unsigned short* __restrict__ wqkv_t,
                            const float* __restrict__ Wproj, unsigned short* __restrict__ wproj_t) {
    __shared__ float tile[32][33];
    const int id = blockIdx.x;
    const int tid = threadIdx.x;
    if (id < 4096) {
        int i = (id * 256 + tid) * 4;
        float4 f = *(const float4*)(x + i);
        ushort4 o;
        o.x = f32_bf16(f.x); o.y = f32_bf16(f.y); o.z = f32_bf16(f.z); o.w = f32_bf16(f.w);
        *(ushort4*)(xbf + i) = o;
        return;
    }
    const float* W; unsigned short* Wt; int K, N, bx, by;
    if (id < 7168) {
        int r = id - 4096; W = Wqkv; Wt = wqkv_t; K = 1024; N = 3072;
        bx = r % 96; by = r / 96;
    } else {
        int r = id - 7168; W = Wproj; Wt = wproj_t; K = 1024; N = 1024;
        bx = r & 31; by = r >> 5;
    }
    int n0 = bx * 32, k0 = by * 32;
    int tx = tid & 31, ty = tid >> 5;
    #pragma unroll
    for (int j = 0; j < 32; j += 8)
        tile[ty + j][tx] = W[(size_t)(k0 + ty + j) * N + n0 + tx];
    __syncthreads();
    #pragma unroll
    for (int j = 0; j < 32; j += 8)
        Wt[(size_t)(n0 + ty + j) * K + k0 + tx] = f32_bf16(tile[tx][ty + j]);
}

// ---------------- GEMM: 2-phase dbuf gll staging; tile 128 x BN (round-13 proven) ----------------
template<int EPI, int BN>
__global__ __launch_bounds__(256) void gemm_bt(
    const unsigned short* __restrict__ A,
    const unsigned short* __restrict__ Bt,
    const float* __restrict__ bias,
    unsigned short* __restrict__ out_bf16,
    float* __restrict__ out_f32,
    int M, int N, int K)
{
    constexpr int NI = (BN == 128) ? 4 : 2;
    constexpr int BSTR = BN * 32;
    __shared__ __align__(16) unsigned short smem[16640];
    unsigned short* AsU = smem;
    unsigned short* BsU = smem + 8192;
    int tid = threadIdx.x;
    int lane = tid & 63, wid = tid >> 6;
    int fr = lane & 15, fg = lane >> 4;
    int row0 = blockIdx.x * 128, col0 = blockIdx.y * BN;
    int wm = (wid >> 1) * 64, wn = (wid & 1) * (BN / 2);

    f32x4 acc[4][NI];
    #pragma unroll
    for (int i = 0; i < 4; ++i)
        #pragma unroll
        for (int j = 0; j < NI; ++j)
            acc[i][j] = (f32x4){0.f, 0.f, 0.f, 0.f};

    const int srw = lane >> 2;
    const int scl = (lane & 3) * 8;
    const int c0 = wid * 2, c1 = wid * 2 + 1;

    auto stage = [&](int buf, int k0) {
        __builtin_amdgcn_global_load_lds(
            (const __attribute__((address_space(1))) void*)(A + (size_t)(row0 + c0 * 16 + srw) * K + k0 + scl),
            (__attribute__((address_space(3))) void*)(AsU + buf * 4096 + c0 * 512), 16, 0, 0);
        __builtin_amdgcn_global_load_lds(
            (const __attribute__((address_space(1))) void*)(A + (size_t)(row0 + c1 * 16 + srw) * K + k0 + scl),
            (__attribute__((address_space(3))) void*)(AsU + buf * 4096 + c1 * 512), 16, 0, 0);
        if (BN == 128) {
            __builtin_amdgcn_global_load_lds(
                (const __attribute__((address_space(1))) void*)(Bt + (size_t)(col0 + c0 * 16 + srw) * K + k0 + scl),
                (__attribute__((address_space(3))) void*)(BsU + buf * BSTR + c0 * 512), 16, 0, 0);
            __builtin_amdgcn_global_load_lds(
                (const __attribute__((address_space(1))) void*)(Bt + (size_t)(col0 + c1 * 16 + srw) * K + k0 + scl),
                (__attribute__((address_space(3))) void*)(BsU + buf * BSTR + c1 * 512), 16, 0, 0);
        } else {
            __builtin_amdgcn_global_load_lds(
                (const __attribute__((address_space(1))) void*)(Bt + (size_t)(col0 + wid * 16 + srw) * K + k0 + scl),
                (__attribute__((address_space(3))) void*)(BsU + buf * BSTR + wid * 512), 16, 0, 0);
        }
    };

    stage(0, 0);
    __syncthreads();

    int cur = 0;
    for (int k0 = 0; k0 < K; k0 += 32) {
        if (k0 + 32 < K) stage(cur ^ 1, k0 + 32);

        bf16x8 af[4], bfr[NI];
        #pragma unroll
        for (int i = 0; i < 4; ++i)
            af[i] = *(const bf16x8*)(AsU + cur * 4096 + (wm + i * 16 + fr) * 32 + fg * 8);
        #pragma unroll
        for (int i = 0; i < NI; ++i)
            bfr[i] = *(const bf16x8*)(BsU + cur * BSTR + (wn + i * 16 + fr) * 32 + fg * 8);
        #pragma unroll
        for (int mi = 0; mi < 4; ++mi)
            #pragma unroll
            for (int ni = 0; ni < NI; ++ni)
                acc[mi][ni] = __builtin_amdgcn_mfma_f32_16x16x32_bf16(af[mi], bfr[ni], acc[mi][ni], 0, 0, 0);

        __syncthreads();
        cur ^= 1;
    }

    if (EPI == 0 && BN == 128 && col0 >= 2048) {
        // V blocks: transpose through LDS, coalesced [d][T] stores
        #pragma unroll
        for (int ni = 0; ni < NI; ++ni) {
            const int cl = wn + ni * 16 + fr;
            const float bv = bias[col0 + cl];
            #pragma unroll
            for (int mi = 0; mi < 4; ++mi) {
                const int rl = wm + mi * 16 + fg * 4;
                bf16x4 pk = {(__bf16)(acc[mi][ni][0] + bv), (__bf16)(acc[mi][ni][1] + bv),
                             (__bf16)(acc[mi][ni][2] + bv), (__bf16)(acc[mi][ni][3] + bv)};
                uint2 w = __builtin_bit_cast(uint2, pk);
                *(unsigned int*)(smem + cl * 130 + rl)     = w.x;
                *(unsigned int*)(smem + cl * 130 + rl + 2) = w.y;
            }
        }
        __syncthreads();
        const int c = tid >> 1, half = tid & 1;
        const int col = col0 + c;
        const int d = col & 63, h2 = (col >> 6) & 15;
        const int bb = row0 >> 11;
        const int t0 = (row0 & 2047) + half * 64;
        unsigned short* dst = out_bf16 + (size_t)2 * BHTD_ +
                              ((size_t)(bb * H_ + h2) * D_ + d) * T_ + t0;
        const unsigned short* src = smem + c * 130 + half * 64;
        #pragma unroll
        for (int j = 0; j < 8; ++j) {
            uint4 v;
            v.x = *(const unsigned int*)(src + j * 8 + 0);
            v.y = *(const unsigned int*)(src + j * 8 + 2);
            v.z = *(const unsigned int*)(src + j * 8 + 4);
            v.w = *(const unsigned int*)(src + j * 8 + 6);
            *(uint4*)(dst + j * 8) = v;
        }
        return;
    }

    #pragma unroll
    for (int mi = 0; mi < 4; ++mi) {
        int rowb = row0 + wm + mi * 16 + fg * 4;
        #pragma unroll
        for (int ni = 0; ni < NI; ++ni) {
            int col = col0 + wn + ni * 16 + fr;
            float bv = bias[col];
            #pragma unroll
            for (int r = 0; r < 4; ++r) {
                float v = acc[mi][ni][r] + bv;
                int rr = rowb + r;
                if (EPI == 0) {
                    int part = col >> 10, c = col & 1023;
                    int h = c >> 6, d = c & 63;
                    int b = rr >> 11, t = rr & 2047;
                    if (part == 0) v *= 0.18033688011112042f;   // fold log2(e)/sqrt(D) into Q
                    size_t idx = (size_t)part * BHTD_ + ((size_t)(b * H_ + h) * T_ + t) * D_ + d;
                    out_bf16[idx] = f32_bf16(v);
                } else {
                    out_f32[(size_t)rr * N + col] = v;
                }
            }
        }
    }
}

// ---------------- causal flash attention v12: v8 dual-stream, KVBLK=128 ----------------
// Identical math/body to the proven v8 (dual 64-row chunks per block, swapped
// QK/PV, no-max softmax, P via per-wave swizzled LDS), but K/V staged as
// 128-kv tiles computed as TWO 64-kv halves per barrier -> barrier count and
// staging-join count halved (33 -> 17). LDS 80KB (2 blocks/CU, grid-matched).
__global__ __launch_bounds__(256) void attn_kernel(
    const unsigned short* __restrict__ qg,
    const unsigned short* __restrict__ kg,
    const unsigned short* __restrict__ vtg,  // [bh][D][T]
    unsigned short* __restrict__ y)
{
    const int id = blockIdx.x;
    const int xcd = id & 7, loc = id >> 3;
    const int bh = xcd * 4 + (loc & 3);      // 4 heads per XCD -> K/V L2-resident
    const int iq0 = loc >> 2;                // [0,16)
    const int iq = (iq0 < 8) ? iq0 : 23 - iq0;
    const int chlo = iq, chhi = 31 - iq;     // 64-row q chunks
    const int b = bh >> 4, h = bh & 15;
    const int tid = threadIdx.x, wid = tid >> 6, lane = tid & 63;
    const int fr = lane & 15, fg = lane >> 4;

    const unsigned short* qp = qg + (size_t)bh * (T_ * D_);
    const char* kpB = (const char*)(kg + (size_t)bh * (T_ * D_));
    const char* vpB = (const char*)(vtg + (size_t)bh * (D_ * T_));

    __shared__ __align__(16) char Ks[2][16384];      // [128 kv][128B], XOR-swizzled
    __shared__ __align__(16) char Vs[2][16384];      // [64 d][256B], XOR-swizzled per 128B half
    __shared__ __align__(16) char Ps[4][32 * 128];   // per-wave P: [stream*16+row][64kv]
    char* Pw = Ps[wid];

    const int rhi = chhi * 64 + wid * 16;
    const int rlo = chlo * 64 + wid * 16;

    // staging geometry: K rows srow+{0,32,64,96} (128B rows); V rows srow+{0,32} x col halves {0,128}
    const int srow = tid >> 3;               // [0,32)
    const int scb  = (tid & 7) * 16;         // byte col in 128B, step 16
    const int sws  = scb ^ ((srow & 7) << 4);

    bf16x8 qhi[2], qlo[2];
    #pragma unroll
    for (int kd = 0; kd < 2; ++kd) {
        qhi[kd] = *(const bf16x8*)(qp + (size_t)(rhi + fr) * D_ + kd * 32 + fg * 8);
        qlo[kd] = *(const bf16x8*)(qp + (size_t)(rlo + fr) * D_ + kd * 32 + fg * 8);
    }

    f32x4 oHi[4], oLo[4];
    float lHi = 0.f, lLo = 0.f;
    #pragma unroll
    for (int n = 0; n < 4; ++n) {
        oHi[n] = (f32x4){0.f, 0.f, 0.f, 0.f};
        oLo[n] = (f32x4){0.f, 0.f, 0.f, 0.f};
    }

    const int ntk = (chhi + 2) >> 1;          // 128-kv tiles

    // prologue: stage tile 0 into buffer 0
    {
        #pragma unroll
        for (int j = 0; j < 4; ++j) {
            uint4 kd = *(const uint4*)(kpB + (size_t)(srow + 32 * j) * 128 + scb);
            *(uint4*)(Ks[0] + (srow + 32 * j) * 128 + sws) = kd;
        }
        #pragma unroll
        for (int jr = 0; jr < 2; ++jr)
            #pragma unroll
            for (int jc = 0; jc < 2; ++jc) {
                uint4 vd = *(const uint4*)(vpB + (size_t)(srow + 32 * jr) * 4096 + jc * 128 + scb);
                *(uint4*)(Vs[0] + (srow + 32 * jr) * 256 + jc * 128 + sws) = vd;
            }
    }
    __syncthreads();

    const unsigned lsw = (unsigned)((fr & 7) << 4);
    int cur = 0;
    for (int t = 0; t < ntk; ++t) {
        // prefetch tile t+1 global->reg (lands under this tile's compute)
        const int kvn = (t + 1 < ntk) ? (t + 1) * 128 : t * 128;
        uint4 pk[4], pv[4];
        #pragma unroll
        for (int j = 0; j < 4; ++j)
            pk[j] = *(const uint4*)(kpB + (size_t)(kvn + srow + 32 * j) * 128 + scb);
        #pragma unroll
        for (int jr = 0; jr < 2; ++jr)
            #pragma unroll
            for (int jc = 0; jc < 2; ++jc)
                pv[jr * 2 + jc] = *(const uint4*)(vpB + (size_t)(srow + 32 * jr) * 4096 +
                                                  (size_t)kvn * 2 + jc * 128 + scb);

        #pragma unroll
        for (int hh = 0; hh < 2; ++hh) {
            const int h64 = 2 * t + hh;
            if (h64 > chhi) break;           // block-uniform (only last tile, even chhi)
            const int kv0 = h64 * 64;
            const char* KbH = Ks[cur] + hh * 8192;   // kv rows [hh*64, hh*64+64)
            const char* Vb  = Vs[cur];
            const int hoff = hh * 128;               // byte col half in V rows
            const bool lo_act = (h64 <= chlo);

            // ---- S^T = mfma(K, Q), both streams ----
            f32x4 sh[4], sl[4];
            #pragma unroll
            for (int n = 0; n < 4; ++n) {
                sh[n] = (f32x4){0.f, 0.f, 0.f, 0.f};
                sl[n] = (f32x4){0.f, 0.f, 0.f, 0.f};
            }
            __builtin_amdgcn_s_setprio(1);
            #pragma unroll
            for (int kd = 0; kd < 2; ++kd)
                #pragma unroll
                for (int n = 0; n < 4; ++n) {
                    bf16x8 kf = *(const bf16x8*)(KbH + (n * 16 + fr) * 128 +
                                                 (((unsigned)(kd * 64 + fg * 16)) ^ lsw));
                    sh[n] = __builtin_amdgcn_mfma_f32_16x16x32_bf16(kf, qhi[kd], sh[n], 0, 0, 0);
                    if (lo_act)
                        sl[n] = __builtin_amdgcn_mfma_f32_16x16x32_bf16(kf, qlo[kd], sl[n], 0, 0, 0);
                }
            __builtin_amdgcn_s_setprio(0);

            // ---- V^T frags (shared by both streams) ----
            bf16x8 vf[4][2];
            #pragma unroll
            for (int nd = 0; nd < 4; ++nd)
                #pragma unroll
                for (int kk = 0; kk < 2; ++kk)
                    vf[nd][kk] = *(const bf16x8*)(Vb + (nd * 16 + fr) * 256 + hoff +
                                                  (((unsigned)(kk * 64 + fg * 16)) ^ lsw));

            // ---- hi: softmax + P write ----
            {
                const bool masked = (h64 == chhi);
                const int qrow = rhi + fr;
                const unsigned prow = (unsigned)fr * 128;
                #pragma unroll
                for (int n = 0; n < 4; ++n) {
                    float x0 = sh[n][0], x1 = sh[n][1], x2 = sh[n][2], x3 = sh[n][3];
                    if (masked) {
                        const int kvb = kv0 + n * 16 + fg * 4;
                        if (kvb     > qrow) x0 = -1e30f;
                        if (kvb + 1 > qrow) x1 = -1e30f;
                        if (kvb + 2 > qrow) x2 = -1e30f;
                        if (kvb + 3 > qrow) x3 = -1e30f;
                    }
                    const float p0 = exp2f(x0), p1 = exp2f(x1);
                    const float p2 = exp2f(x2), p3 = exp2f(x3);
                    lHi += (p0 + p1) + (p2 + p3);
                    bf16x4 pk4 = {(__bf16)p0, (__bf16)p1, (__bf16)p2, (__bf16)p3};
                    *(uint2*)(Pw + ((prow + (unsigned)(n * 32 + fg * 8)) ^ lsw)) =
                        __builtin_bit_cast(uint2, pk4);
                }
            }
            // ---- hi: PV ----
            {
                const unsigned prow = (unsigned)fr * 128;
                __builtin_amdgcn_s_setprio(1);
                #pragma unroll
                for (int kk = 0; kk < 2; ++kk) {
                    bf16x8 pb = *(const bf16x8*)(Pw + ((prow + (unsigned)(kk * 64 + fg * 16)) ^ lsw));
                    #pragma unroll
                    for (int nd = 0; nd < 4; ++nd)
                        oHi[nd] = __builtin_amdgcn_mfma_f32_16x16x32_bf16(vf[nd][kk], pb, oHi[nd], 0, 0, 0);
                }
                __builtin_amdgcn_s_setprio(0);
            }
            // ---- lo: softmax + P write + PV ----
            if (lo_act) {
                const bool masked = (h64 == chlo);
                const int qrow = rlo + fr;
                const unsigned prow = (unsigned)(16 + fr) * 128;
                #pragma unroll
                for (int n = 0; n < 4; ++n) {
                    float x0 = sl[n][0], x1 = sl[n][1], x2 = sl[n][2], x3 = sl[n][3];
                    if (masked) {
                        const int kvb = kv0 + n * 16 + fg * 4;
                        if (kvb     > qrow) x0 = -1e30f;
                        if (kvb + 1 > qrow) x1 = -1e30f;
                        if (kvb + 2 > qrow) x2 = -1e30f;
                        if (kvb + 3 > qrow) x3 = -1e30f;
                    }
                    const float p0 = exp2f(x0), p1 = exp2f(x1);
                    const float p2 = exp2f(x2), p3 = exp2f(x3);
                    lLo += (p0 + p1) + (p2 + p3);
                    bf16x4 pk4 = {(__bf16)p0, (__bf16)p1, (__bf16)p2, (__bf16)p3};
                    *(uint2*)(Pw + ((prow + (unsigned)(n * 32 + fg * 8)) ^ lsw)) =
                        __builtin_bit_cast(uint2, pk4);
                }
                __builtin_amdgcn_s_setprio(1);
                #pragma unroll
                for (int kk = 0; kk < 2; ++kk) {
                    bf16x8 pb = *(const bf16x8*)(Pw + ((prow + (unsigned)(kk * 64 + fg * 16)) ^ lsw));
                    #pragma unroll
                    for (int nd = 0; nd < 4; ++nd)
                        oLo[nd] = __builtin_amdgcn_mfma_f32_16x16x32_bf16(vf[nd][kk], pb, oLo[nd], 0, 0, 0);
                }
                __builtin_amdgcn_s_setprio(0);
            }
        }

        // write prefetched tile into the other buffer, then barrier
        {
            char* Kn = Ks[cur ^ 1];
            char* Vn = Vs[cur ^ 1];
            #pragma unroll
            for (int j = 0; j < 4; ++j)
                *(uint4*)(Kn + (srow + 32 * j) * 128 + sws) = pk[j];
            #pragma unroll
            for (int jr = 0; jr < 2; ++jr)
                #pragma unroll
                for (int jc = 0; jc < 2; ++jc)
                    *(uint4*)(Vn + (srow + 32 * jr) * 256 + jc * 128 + sws) = pv[jr * 2 + jc];
        }
        __syncthreads();
        cur ^= 1;
    }

    // ---- epilogue: reduce l over fg groups, normalize, packed stores ----
    #pragma unroll
    for (int s = 0; s < 2; ++s) {
        float rs = s ? lLo : lHi;
        rs += __shfl_xor(rs, 16);
        rs += __shfl_xor(rs, 32);
        const float inv = 1.f / rs;
        const int trow = (s ? rlo : rhi) + fr;
        f32x4* oT = s ? oLo : oHi;
        #pragma unroll
        for (int nd = 0; nd < 4; ++nd) {
            bf16x4 ov = {(__bf16)(oT[nd][0] * inv), (__bf16)(oT[nd][1] * inv),
                         (__bf16)(oT[nd][2] * inv), (__bf16)(oT[nd][3] * inv)};
            *(uint2*)(y + ((size_t)b * T_ + trow) * C_ + h * 64 + nd * 16 + fg * 4) =
                __builtin_bit_cast(uint2, ov);
        }
    }
}

// ---------------- launch ----------------
extern "C" void kernel_launch(void* const* d_in, const int* in_sizes, int n_in,
                              void* d_out, int out_size, void* d_ws, size_t ws_size,
                              hipStream_t stream) {
    const float* x     = (const float*)d_in[0];
    const float* Wqkv  = (const float*)d_in[1];
    const float* bqkv  = (const float*)d_in[2];
    const float* Wproj = (const float*)d_in[3];
    const float* bproj = (const float*)d_in[4];
    float* out = (float*)d_out;

    char* ws = (char*)d_ws;
    unsigned short* x_bf    = (unsigned short*)(ws);                 //  8 MB
    unsigned short* wqkv_t  = (unsigned short*)(ws + 8388608);       //  6 MB
    unsigned short* wproj_t = (unsigned short*)(ws + 14680064);      //  2 MB
    unsigned short* qkv     = (unsigned short*)(ws + 16777216);      // 24 MB
    unsigned short* ybuf    = (unsigned short*)(ws + 41943040);      //  8 MB

    prep_kernel<<<dim3(8192), 256, 0, stream>>>(x, x_bf, Wqkv, wqkv_t, Wproj, wproj_t);

    gemm_bt<0, 128><<<dim3(M_ / 128, 3072 / 128), 256, 0, stream>>>(
        x_bf, wqkv_t, bqkv, qkv, nullptr, M_, 3072, 1024);

    attn_kernel<<<dim3(512), 256, 0, stream>>>(
        qkv, qkv + (size_t)BHTD_, qkv + 2 * (size_t)BHTD_, ybuf);

    gemm_bt<1, 64><<<dim3(M_ / 128, 1024 / 64), 256, 0, stream>>>(
        ybuf, wproj_t, bproj, nullptr, out, M_, 1024, 1024);
}

// Round 16
// 117.295 us; speedup vs baseline: 1.0897x; 1.0265x over previous
//
#include <hip/hip_runtime.h>
#include <stdint.h>

#define B_ 2
#define T_ 2048
#define C_ 1024
#define H_ 16
#define D_ 64
#define M_ (B_*T_)
#define BHTD_ (B_*H_*T_*D_)

#define AS1 __attribute__((address_space(1)))
#define AS3 __attribute__((address_space(3)))

typedef __bf16 bf16x8 __attribute__((ext_vector_type(8)));
typedef __bf16 bf16x4 __attribute__((ext_vector_type(4)));
typedef float f32x4 __attribute__((ext_vector_type(4)));

static __device__ __forceinline__ unsigned short f32_bf16(float f) {
    unsigned int u = __float_as_uint(f);
    u += 0x7FFFu + ((u >> 16) & 1u);   // round-to-nearest-even
    return (unsigned short)(u >> 16);
}

// ---------------- fused prep: cast x + transpose both W (one launch) ----------------
__global__ void prep_kernel(const float* __restrict__ x, unsigned short* __restrict__ xbf,
                            const float* __restrict__ Wqkv, unsigned short* __restrict__ wqkv_t,
                            const float* __restrict__ Wproj, unsigned short* __restrict__ wproj_t) {
    __shared__ float tile[32][33];
    const int id = blockIdx.x;
    const int tid = threadIdx.x;
    if (id < 4096) {
        int i = (id * 256 + tid) * 4;
        float4 f = *(const float4*)(x + i);
        ushort4 o;
        o.x = f32_bf16(f.x); o.y = f32_bf16(f.y); o.z = f32_bf16(f.z); o.w = f32_bf16(f.w);
        *(ushort4*)(xbf + i) = o;
        return;
    }
    const float* W; unsigned short* Wt; int K, N, bx, by;
    if (id < 7168) {
        int r = id - 4096; W = Wqkv; Wt = wqkv_t; K = 1024; N = 3072;
        bx = r % 96; by = r / 96;
    } else {
        int r = id - 7168; W = Wproj; Wt = wproj_t; K = 1024; N = 1024;
        bx = r & 31; by = r >> 5;
    }
    int n0 = bx * 32, k0 = by * 32;
    int tx = tid & 31, ty = tid >> 5;
    #pragma unroll
    for (int j = 0; j < 32; j += 8)
        tile[ty + j][tx] = W[(size_t)(k0 + ty + j) * N + n0 + tx];
    __syncthreads();
    #pragma unroll
    for (int j = 0; j < 32; j += 8)
        Wt[(size_t)(n0 + ty + j) * K + k0 + tx] = f32_bf16(tile[tx][ty + j]);
}

// ---------------- GEMM: 2-phase dbuf gll staging; tile 128 x BN (round-13 proven) ----------------
template<int EPI, int BN>
__global__ __launch_bounds__(256) void gemm_bt(
    const unsigned short* __restrict__ A,
    const unsigned short* __restrict__ Bt,
    const float* __restrict__ bias,
    unsigned short* __restrict__ out_bf16,
    float* __restrict__ out_f32,
    int M, int N, int K)
{
    constexpr int NI = (BN == 128) ? 4 : 2;
    constexpr int BSTR = BN * 32;
    __shared__ __align__(16) unsigned short smem[16640];
    unsigned short* AsU = smem;
    unsigned short* BsU = smem + 8192;
    int tid = threadIdx.x;
    int lane = tid & 63, wid = tid >> 6;
    int fr = lane & 15, fg = lane >> 4;
    int row0 = blockIdx.x * 128, col0 = blockIdx.y * BN;
    int wm = (wid >> 1) * 64, wn = (wid & 1) * (BN / 2);

    f32x4 acc[4][NI];
    #pragma unroll
    for (int i = 0; i < 4; ++i)
        #pragma unroll
        for (int j = 0; j < NI; ++j)
            acc[i][j] = (f32x4){0.f, 0.f, 0.f, 0.f};

    const int srw = lane >> 2;
    const int scl = (lane & 3) * 8;
    const int c0 = wid * 2, c1 = wid * 2 + 1;

    auto stage = [&](int buf, int k0) {
        __builtin_amdgcn_global_load_lds(
            (const AS1 void*)(A + (size_t)(row0 + c0 * 16 + srw) * K + k0 + scl),
            (AS3 void*)(AsU + buf * 4096 + c0 * 512), 16, 0, 0);
        __builtin_amdgcn_global_load_lds(
            (const AS1 void*)(A + (size_t)(row0 + c1 * 16 + srw) * K + k0 + scl),
            (AS3 void*)(AsU + buf * 4096 + c1 * 512), 16, 0, 0);
        if (BN == 128) {
            __builtin_amdgcn_global_load_lds(
                (const AS1 void*)(Bt + (size_t)(col0 + c0 * 16 + srw) * K + k0 + scl),
                (AS3 void*)(BsU + buf * BSTR + c0 * 512), 16, 0, 0);
            __builtin_amdgcn_global_load_lds(
                (const AS1 void*)(Bt + (size_t)(col0 + c1 * 16 + srw) * K + k0 + scl),
                (AS3 void*)(BsU + buf * BSTR + c1 * 512), 16, 0, 0);
        } else {
            __builtin_amdgcn_global_load_lds(
                (const AS1 void*)(Bt + (size_t)(col0 + wid * 16 + srw) * K + k0 + scl),
                (AS3 void*)(BsU + buf * BSTR + wid * 512), 16, 0, 0);
        }
    };

    stage(0, 0);
    __syncthreads();

    int cur = 0;
    for (int k0 = 0; k0 < K; k0 += 32) {
        if (k0 + 32 < K) stage(cur ^ 1, k0 + 32);

        bf16x8 af[4], bfr[NI];
        #pragma unroll
        for (int i = 0; i < 4; ++i)
            af[i] = *(const bf16x8*)(AsU + cur * 4096 + (wm + i * 16 + fr) * 32 + fg * 8);
        #pragma unroll
        for (int i = 0; i < NI; ++i)
            bfr[i] = *(const bf16x8*)(BsU + cur * BSTR + (wn + i * 16 + fr) * 32 + fg * 8);
        #pragma unroll
        for (int mi = 0; mi < 4; ++mi)
            #pragma unroll
            for (int ni = 0; ni < NI; ++ni)
                acc[mi][ni] = __builtin_amdgcn_mfma_f32_16x16x32_bf16(af[mi], bfr[ni], acc[mi][ni], 0, 0, 0);

        __syncthreads();
        cur ^= 1;
    }

    if (EPI == 0 && BN == 128 && col0 >= 2048) {
        // V blocks: transpose through LDS, coalesced [d][T] stores
        #pragma unroll
        for (int ni = 0; ni < NI; ++ni) {
            const int cl = wn + ni * 16 + fr;
            const float bv = bias[col0 + cl];
            #pragma unroll
            for (int mi = 0; mi < 4; ++mi) {
                const int rl = wm + mi * 16 + fg * 4;
                bf16x4 pk = {(__bf16)(acc[mi][ni][0] + bv), (__bf16)(acc[mi][ni][1] + bv),
                             (__bf16)(acc[mi][ni][2] + bv), (__bf16)(acc[mi][ni][3] + bv)};
                uint2 w = __builtin_bit_cast(uint2, pk);
                *(unsigned int*)(smem + cl * 130 + rl)     = w.x;
                *(unsigned int*)(smem + cl * 130 + rl + 2) = w.y;
            }
        }
        __syncthreads();
        const int c = tid >> 1, half = tid & 1;
        const int col = col0 + c;
        const int d = col & 63, h2 = (col >> 6) & 15;
        const int bb = row0 >> 11;
        const int t0 = (row0 & 2047) + half * 64;
        unsigned short* dst = out_bf16 + (size_t)2 * BHTD_ +
                              ((size_t)(bb * H_ + h2) * D_ + d) * T_ + t0;
        const unsigned short* src = smem + c * 130 + half * 64;
        #pragma unroll
        for (int j = 0; j < 8; ++j) {
            uint4 v;
            v.x = *(const unsigned int*)(src + j * 8 + 0);
            v.y = *(const unsigned int*)(src + j * 8 + 2);
            v.z = *(const unsigned int*)(src + j * 8 + 4);
            v.w = *(const unsigned int*)(src + j * 8 + 6);
            *(uint4*)(dst + j * 8) = v;
        }
        return;
    }

    #pragma unroll
    for (int mi = 0; mi < 4; ++mi) {
        int rowb = row0 + wm + mi * 16 + fg * 4;
        #pragma unroll
        for (int ni = 0; ni < NI; ++ni) {
            int col = col0 + wn + ni * 16 + fr;
            float bv = bias[col];
            #pragma unroll
            for (int r = 0; r < 4; ++r) {
                float v = acc[mi][ni][r] + bv;
                int rr = rowb + r;
                if (EPI == 0) {
                    int part = col >> 10, c = col & 1023;
                    int h = c >> 6, d = c & 63;
                    int b = rr >> 11, t = rr & 2047;
                    if (part == 0) v *= 0.18033688011112042f;   // fold log2(e)/sqrt(D) into Q
                    size_t idx = (size_t)part * BHTD_ + ((size_t)(b * H_ + h) * T_ + t) * D_ + d;
                    out_bf16[idx] = f32_bf16(v);
                } else {
                    out_f32[(size_t)rr * N + col] = v;
                }
            }
        }
    }
}

// ---------------- causal flash attention v13: v8 structure + raw v_exp + gll staging ----------------
// Identical math to round-13 v8 (dual-stream balanced blocks, swapped QK/PV,
// no-max softmax, P via per-wave swizzled LDS, setprio). Changes:
//  (a) exp2f -> __builtin_amdgcn_exp2f (raw v_exp_f32; OCML exp2f has a
//      range-fixup branch that inflated VALU ~3x). Masked -1e30 -> exactly 0.
//  (b) staging via global_load_lds with pre-swizzled SOURCE (rule #21, v10-
//      verified): removes 8 global reg-loads + 8 swizzled ds_writes + 16 VGPRs.
__global__ __launch_bounds__(256) void attn_kernel(
    const unsigned short* __restrict__ qg,
    const unsigned short* __restrict__ kg,
    const unsigned short* __restrict__ vtg,  // [bh][D][T]
    unsigned short* __restrict__ y)
{
    const int id = blockIdx.x;
    const int xcd = id & 7, loc = id >> 3;
    const int bh = xcd * 4 + (loc & 3);      // 4 heads per XCD -> K/V L2-resident
    const int iq0 = loc >> 2;                // [0,16)
    const int iq = (iq0 < 8) ? iq0 : 23 - iq0;
    const int chlo = iq, chhi = 31 - iq;     // 64-row q chunks
    const int b = bh >> 4, h = bh & 15;
    const int tid = threadIdx.x, wid = tid >> 6, lane = tid & 63;
    const int fr = lane & 15, fg = lane >> 4;

    const unsigned short* qp = qg + (size_t)bh * (T_ * D_);
    const char* kpB = (const char*)(kg + (size_t)bh * (T_ * D_));
    const char* vpB = (const char*)(vtg + (size_t)bh * (D_ * T_));

    __shared__ __align__(16) char Ks[2][8192];       // [kv][128B], XOR-swizzled
    __shared__ __align__(16) char Vs[2][8192];       // [d][128B], XOR-swizzled
    __shared__ __align__(16) char Ps[4][32 * 128];   // per-wave P: [stream*16+row][kv]
    char* Pw = Ps[wid];

    const int rhi = chhi * 64 + wid * 16;
    const int rlo = chlo * 64 + wid * 16;

    bf16x8 qhi[2], qlo[2];
    #pragma unroll
    for (int kd = 0; kd < 2; ++kd) {
        qhi[kd] = *(const bf16x8*)(qp + (size_t)(rhi + fr) * D_ + kd * 32 + fg * 8);
        qlo[kd] = *(const bf16x8*)(qp + (size_t)(rlo + fr) * D_ + kd * 32 + fg * 8);
    }

    f32x4 oHi[4], oLo[4];
    float lHi = 0.f, lLo = 0.f;
    #pragma unroll
    for (int n = 0; n < 4; ++n) {
        oHi[n] = (f32x4){0.f, 0.f, 0.f, 0.f};
        oLo[n] = (f32x4){0.f, 0.f, 0.f, 0.f};
    }

    const int ntk  = chhi + 1;
    const int ntlo = chlo + 1;

    // gll staging: per wave 2 K-chunks + 2 V-chunks of 8 rows (1KB each).
    // LDS dest linear (base + lane*16); SOURCE pre-swizzled so swizzled READS work.
    const int srow8 = lane >> 3;             // row within 8-row chunk [0,8)
    const int scol  = (lane & 7) * 16;       // byte col within 128B row
    const int ssw   = srow8 << 4;            // == (row&7)<<4 (rbase % 8 == 0)

    auto stage = [&](int buf, int kv0) {
        #pragma unroll
        for (int bc = 0; bc < 2; ++bc) {
            const int rbase = wid * 16 + bc * 8;
            __builtin_amdgcn_global_load_lds(
                (const AS1 void*)(kpB + (size_t)(kv0 + rbase + srow8) * 128 + (scol ^ ssw)),
                (AS3 void*)(Ks[buf] + rbase * 128), 16, 0, 0);
            __builtin_amdgcn_global_load_lds(
                (const AS1 void*)(vpB + (size_t)(rbase + srow8) * 4096 + (size_t)kv0 * 2 + (scol ^ ssw)),
                (AS3 void*)(Vs[buf] + rbase * 128), 16, 0, 0);
        }
    };

    stage(0, 0);
    __syncthreads();

    const unsigned lsw = (unsigned)((fr & 7) << 4);
    int cur = 0;
    for (int t = 0; t < ntk; ++t) {
        const int kv0 = t * 64;
        if (t + 1 < ntk) stage(cur ^ 1, kv0 + 64);   // async; drains at loop-end barrier

        const char* Kb = Ks[cur];
        const char* Vb = Vs[cur];
        const bool lo_act = (t < ntlo);

        // ---- S^T = mfma(K, Q), both streams ----
        f32x4 sh[4], sl[4];
        #pragma unroll
        for (int n = 0; n < 4; ++n) {
            sh[n] = (f32x4){0.f, 0.f, 0.f, 0.f};
            sl[n] = (f32x4){0.f, 0.f, 0.f, 0.f};
        }
        __builtin_amdgcn_s_setprio(1);
        #pragma unroll
        for (int kd = 0; kd < 2; ++kd)
            #pragma unroll
            for (int n = 0; n < 4; ++n) {
                bf16x8 kf = *(const bf16x8*)(Kb + (n * 16 + fr) * 128 +
                                             (((unsigned)(kd * 64 + fg * 16)) ^ lsw));
                sh[n] = __builtin_amdgcn_mfma_f32_16x16x32_bf16(kf, qhi[kd], sh[n], 0, 0, 0);
                if (lo_act)
                    sl[n] = __builtin_amdgcn_mfma_f32_16x16x32_bf16(kf, qlo[kd], sl[n], 0, 0, 0);
            }
        __builtin_amdgcn_s_setprio(0);

        // ---- V^T frags (shared by both streams) ----
        bf16x8 vf[4][2];
        #pragma unroll
        for (int nd = 0; nd < 4; ++nd)
            #pragma unroll
            for (int kk = 0; kk < 2; ++kk)
                vf[nd][kk] = *(const bf16x8*)(Vb + (nd * 16 + fr) * 128 +
                                              (((unsigned)(kk * 64 + fg * 16)) ^ lsw));

        // ---- hi: softmax + P write ----
        {
            const bool masked = (t == chhi);
            const int qrow = rhi + fr;
            const unsigned prow = (unsigned)fr * 128;
            #pragma unroll
            for (int n = 0; n < 4; ++n) {
                float x0 = sh[n][0], x1 = sh[n][1], x2 = sh[n][2], x3 = sh[n][3];
                if (masked) {
                    const int kvb = kv0 + n * 16 + fg * 4;
                    if (kvb     > qrow) x0 = -1e30f;
                    if (kvb + 1 > qrow) x1 = -1e30f;
                    if (kvb + 2 > qrow) x2 = -1e30f;
                    if (kvb + 3 > qrow) x3 = -1e30f;
                }
                const float p0 = __builtin_amdgcn_exp2f(x0);
                const float p1 = __builtin_amdgcn_exp2f(x1);
                const float p2 = __builtin_amdgcn_exp2f(x2);
                const float p3 = __builtin_amdgcn_exp2f(x3);
                lHi += (p0 + p1) + (p2 + p3);
                bf16x4 pk4 = {(__bf16)p0, (__bf16)p1, (__bf16)p2, (__bf16)p3};
                *(uint2*)(Pw + ((prow + (unsigned)(n * 32 + fg * 8)) ^ lsw)) =
                    __builtin_bit_cast(uint2, pk4);
            }
        }
        // ---- hi: PV ----
        {
            const unsigned prow = (unsigned)fr * 128;
            __builtin_amdgcn_s_setprio(1);
            #pragma unroll
            for (int kk = 0; kk < 2; ++kk) {
                bf16x8 pb = *(const bf16x8*)(Pw + ((prow + (unsigned)(kk * 64 + fg * 16)) ^ lsw));
                #pragma unroll
                for (int nd = 0; nd < 4; ++nd)
                    oHi[nd] = __builtin_amdgcn_mfma_f32_16x16x32_bf16(vf[nd][kk], pb, oHi[nd], 0, 0, 0);
            }
            __builtin_amdgcn_s_setprio(0);
        }
        // ---- lo: softmax + P write + PV ----
        if (lo_act) {
            const bool masked = (t == chlo);
            const int qrow = rlo + fr;
            const unsigned prow = (unsigned)(16 + fr) * 128;
            #pragma unroll
            for (int n = 0; n < 4; ++n) {
                float x0 = sl[n][0], x1 = sl[n][1], x2 = sl[n][2], x3 = sl[n][3];
                if (masked) {
                    const int kvb = kv0 + n * 16 + fg * 4;
                    if (kvb     > qrow) x0 = -1e30f;
                    if (kvb + 1 > qrow) x1 = -1e30f;
                    if (kvb + 2 > qrow) x2 = -1e30f;
                    if (kvb + 3 > qrow) x3 = -1e30f;
                }
                const float p0 = __builtin_amdgcn_exp2f(x0);
                const float p1 = __builtin_amdgcn_exp2f(x1);
                const float p2 = __builtin_amdgcn_exp2f(x2);
                const float p3 = __builtin_amdgcn_exp2f(x3);
                lLo += (p0 + p1) + (p2 + p3);
                bf16x4 pk4 = {(__bf16)p0, (__bf16)p1, (__bf16)p2, (__bf16)p3};
                *(uint2*)(Pw + ((prow + (unsigned)(n * 32 + fg * 8)) ^ lsw)) =
                    __builtin_bit_cast(uint2, pk4);
            }
            __builtin_amdgcn_s_setprio(1);
            #pragma unroll
            for (int kk = 0; kk < 2; ++kk) {
                bf16x8 pb = *(const bf16x8*)(Pw + ((prow + (unsigned)(kk * 64 + fg * 16)) ^ lsw));
                #pragma unroll
                for (int nd = 0; nd < 4; ++nd)
                    oLo[nd] = __builtin_amdgcn_mfma_f32_16x16x32_bf16(vf[nd][kk], pb, oLo[nd], 0, 0, 0);
            }
            __builtin_amdgcn_s_setprio(0);
        }

        __syncthreads();   // drains prefetch gll; all waves done with cur buffer
        cur ^= 1;
    }

    // ---- epilogue: reduce l over fg groups, normalize, packed stores ----
    #pragma unroll
    for (int s = 0; s < 2; ++s) {
        float rs = s ? lLo : lHi;
        rs += __shfl_xor(rs, 16);
        rs += __shfl_xor(rs, 32);
        const float inv = 1.f / rs;
        const int trow = (s ? rlo : rhi) + fr;
        f32x4* oT = s ? oLo : oHi;
        #pragma unroll
        for (int nd = 0; nd < 4; ++nd) {
            bf16x4 ov = {(__bf16)(oT[nd][0] * inv), (__bf16)(oT[nd][1] * inv),
                         (__bf16)(oT[nd][2] * inv), (__bf16)(oT[nd][3] * inv)};
            *(uint2*)(y + ((size_t)b * T_ + trow) * C_ + h * 64 + nd * 16 + fg * 4) =
                __builtin_bit_cast(uint2, ov);
        }
    }
}

// ---------------- launch ----------------
extern "C" void kernel_launch(void* const* d_in, const int* in_sizes, int n_in,
                              void* d_out, int out_size, void* d_ws, size_t ws_size,
                              hipStream_t stream) {
    const float* x     = (const float*)d_in[0];
    const float* Wqkv  = (const float*)d_in[1];
    const float* bqkv  = (const float*)d_in[2];
    const float* Wproj = (const float*)d_in[3];
    const float* bproj = (const float*)d_in[4];
    float* out = (float*)d_out;

    char* ws = (char*)d_ws;
    unsigned short* x_bf    = (unsigned short*)(ws);                 //  8 MB
    unsigned short* wqkv_t  = (unsigned short*)(ws + 8388608);       //  6 MB
    unsigned short* wproj_t = (unsigned short*)(ws + 14680064);      //  2 MB
    unsigned short* qkv     = (unsigned short*)(ws + 16777216);      // 24 MB
    unsigned short* ybuf    = (unsigned short*)(ws + 41943040);      //  8 MB

    prep_kernel<<<dim3(8192), 256, 0, stream>>>(x, x_bf, Wqkv, wqkv_t, Wproj, wproj_t);

    gemm_bt<0, 128><<<dim3(M_ / 128, 3072 / 128), 256, 0, stream>>>(
        x_bf, wqkv_t, bqkv, qkv, nullptr, M_, 3072, 1024);

    attn_kernel<<<dim3(512), 256, 0, stream>>>(
        qkv, qkv + (size_t)BHTD_, qkv + 2 * (size_t)BHTD_, ybuf);

    gemm_bt<1, 64><<<dim3(M_ / 128, 1024 / 64), 256, 0, stream>>>(
        ybuf, wproj_t, bproj, nullptr, out, M_, 1024, 1024);
}

// Round 17
// 116.073 us; speedup vs baseline: 1.1012x; 1.0105x over previous
//
#include <hip/hip_runtime.h>
#include <stdint.h>

#define B_ 2
#define T_ 2048
#define C_ 1024
#define H_ 16
#define D_ 64
#define M_ (B_*T_)
#define BHTD_ (B_*H_*T_*D_)

#define AS1 __attribute__((address_space(1)))
#define AS3 __attribute__((address_space(3)))

typedef __bf16 bf16x8 __attribute__((ext_vector_type(8)));
typedef __bf16 bf16x4 __attribute__((ext_vector_type(4)));
typedef float f32x4 __attribute__((ext_vector_type(4)));

static __device__ __forceinline__ unsigned short f32_bf16(float f) {
    unsigned int u = __float_as_uint(f);
    u += 0x7FFFu + ((u >> 16) & 1u);   // round-to-nearest-even
    return (unsigned short)(u >> 16);
}

// ---------------- fused prep: cast x + transpose both W (one launch) ----------------
__global__ void prep_kernel(const float* __restrict__ x, unsigned short* __restrict__ xbf,
                            const float* __restrict__ Wqkv, unsigned short* __restrict__ wqkv_t,
                            const float* __restrict__ Wproj, unsigned short* __restrict__ wproj_t) {
    __shared__ float tile[32][33];
    const int id = blockIdx.x;
    const int tid = threadIdx.x;
    if (id < 4096) {
        int i = (id * 256 + tid) * 4;
        float4 f = *(const float4*)(x + i);
        ushort4 o;
        o.x = f32_bf16(f.x); o.y = f32_bf16(f.y); o.z = f32_bf16(f.z); o.w = f32_bf16(f.w);
        *(ushort4*)(xbf + i) = o;
        return;
    }
    const float* W; unsigned short* Wt; int K, N, bx, by;
    if (id < 7168) {
        int r = id - 4096; W = Wqkv; Wt = wqkv_t; K = 1024; N = 3072;
        bx = r % 96; by = r / 96;
    } else {
        int r = id - 7168; W = Wproj; Wt = wproj_t; K = 1024; N = 1024;
        bx = r & 31; by = r >> 5;
    }
    int n0 = bx * 32, k0 = by * 32;
    int tx = tid & 31, ty = tid >> 5;
    #pragma unroll
    for (int j = 0; j < 32; j += 8)
        tile[ty + j][tx] = W[(size_t)(k0 + ty + j) * N + n0 + tx];
    __syncthreads();
    #pragma unroll
    for (int j = 0; j < 32; j += 8)
        Wt[(size_t)(n0 + ty + j) * K + k0 + tx] = f32_bf16(tile[tx][ty + j]);
}

// ---------------- GEMM: 2-phase dbuf gll staging; tile 128 x BN ----------------
// Round 17: gemm0 also at BN=64 -> grid 1536 blocks = 4+ blocks/CU TLP
// (was 768 = 3/CU, latency-exposed at MfmaUtil 17.5%). V-transpose epilogue
// generalized to any BN.
template<int EPI, int BN>
__global__ __launch_bounds__(256) void gemm_bt(
    const unsigned short* __restrict__ A,
    const unsigned short* __restrict__ Bt,
    const float* __restrict__ bias,
    unsigned short* __restrict__ out_bf16,
    float* __restrict__ out_f32,
    int M, int N, int K)
{
    constexpr int NI = (BN == 128) ? 4 : 2;
    constexpr int BSTR = BN * 32;
    __shared__ __align__(16) unsigned short smem[16640];
    unsigned short* AsU = smem;
    unsigned short* BsU = smem + 8192;
    int tid = threadIdx.x;
    int lane = tid & 63, wid = tid >> 6;
    int fr = lane & 15, fg = lane >> 4;
    int row0 = blockIdx.x * 128, col0 = blockIdx.y * BN;
    int wm = (wid >> 1) * 64, wn = (wid & 1) * (BN / 2);

    f32x4 acc[4][NI];
    #pragma unroll
    for (int i = 0; i < 4; ++i)
        #pragma unroll
        for (int j = 0; j < NI; ++j)
            acc[i][j] = (f32x4){0.f, 0.f, 0.f, 0.f};

    const int srw = lane >> 2;
    const int scl = (lane & 3) * 8;
    const int c0 = wid * 2, c1 = wid * 2 + 1;

    auto stage = [&](int buf, int k0) {
        __builtin_amdgcn_global_load_lds(
            (const AS1 void*)(A + (size_t)(row0 + c0 * 16 + srw) * K + k0 + scl),
            (AS3 void*)(AsU + buf * 4096 + c0 * 512), 16, 0, 0);
        __builtin_amdgcn_global_load_lds(
            (const AS1 void*)(A + (size_t)(row0 + c1 * 16 + srw) * K + k0 + scl),
            (AS3 void*)(AsU + buf * 4096 + c1 * 512), 16, 0, 0);
        if (BN == 128) {
            __builtin_amdgcn_global_load_lds(
                (const AS1 void*)(Bt + (size_t)(col0 + c0 * 16 + srw) * K + k0 + scl),
                (AS3 void*)(BsU + buf * BSTR + c0 * 512), 16, 0, 0);
            __builtin_amdgcn_global_load_lds(
                (const AS1 void*)(Bt + (size_t)(col0 + c1 * 16 + srw) * K + k0 + scl),
                (AS3 void*)(BsU + buf * BSTR + c1 * 512), 16, 0, 0);
        } else {
            __builtin_amdgcn_global_load_lds(
                (const AS1 void*)(Bt + (size_t)(col0 + wid * 16 + srw) * K + k0 + scl),
                (AS3 void*)(BsU + buf * BSTR + wid * 512), 16, 0, 0);
        }
    };

    stage(0, 0);
    __syncthreads();

    int cur = 0;
    for (int k0 = 0; k0 < K; k0 += 32) {
        if (k0 + 32 < K) stage(cur ^ 1, k0 + 32);

        bf16x8 af[4], bfr[NI];
        #pragma unroll
        for (int i = 0; i < 4; ++i)
            af[i] = *(const bf16x8*)(AsU + cur * 4096 + (wm + i * 16 + fr) * 32 + fg * 8);
        #pragma unroll
        for (int i = 0; i < NI; ++i)
            bfr[i] = *(const bf16x8*)(BsU + cur * BSTR + (wn + i * 16 + fr) * 32 + fg * 8);
        #pragma unroll
        for (int mi = 0; mi < 4; ++mi)
            #pragma unroll
            for (int ni = 0; ni < NI; ++ni)
                acc[mi][ni] = __builtin_amdgcn_mfma_f32_16x16x32_bf16(af[mi], bfr[ni], acc[mi][ni], 0, 0, 0);

        __syncthreads();
        cur ^= 1;
    }

    if (EPI == 0 && col0 >= 2048) {
        // ---- V blocks: transpose through LDS, coalesced [d][T] stores ----
        #pragma unroll
        for (int ni = 0; ni < NI; ++ni) {
            const int cl = wn + ni * 16 + fr;
            const float bv = bias[col0 + cl];
            #pragma unroll
            for (int mi = 0; mi < 4; ++mi) {
                const int rl = wm + mi * 16 + fg * 4;
                bf16x4 pk = {(__bf16)(acc[mi][ni][0] + bv), (__bf16)(acc[mi][ni][1] + bv),
                             (__bf16)(acc[mi][ni][2] + bv), (__bf16)(acc[mi][ni][3] + bv)};
                uint2 w = __builtin_bit_cast(uint2, pk);
                *(unsigned int*)(smem + cl * 130 + rl)     = w.x;
                *(unsigned int*)(smem + cl * 130 + rl + 2) = w.y;
            }
        }
        __syncthreads();
        constexpr int TPC = 256 / BN;          // threads per column
        constexpr int SEG = 128 / TPC;         // t-values per thread (contiguous)
        const int c = tid / TPC, seg = tid % TPC;
        const int col = col0 + c;
        const int d = col & 63, h2 = (col >> 6) & 15;
        const int bb = row0 >> 11;
        const int t0 = (row0 & 2047) + seg * SEG;
        unsigned short* dst = out_bf16 + (size_t)2 * BHTD_ +
                              ((size_t)(bb * H_ + h2) * D_ + d) * T_ + t0;
        const unsigned short* src = smem + c * 130 + seg * SEG;
        #pragma unroll
        for (int j = 0; j < SEG / 8; ++j) {
            uint4 v;
            v.x = *(const unsigned int*)(src + j * 8 + 0);
            v.y = *(const unsigned int*)(src + j * 8 + 2);
            v.z = *(const unsigned int*)(src + j * 8 + 4);
            v.w = *(const unsigned int*)(src + j * 8 + 6);
            *(uint4*)(dst + j * 8) = v;
        }
        return;
    }

    #pragma unroll
    for (int mi = 0; mi < 4; ++mi) {
        int rowb = row0 + wm + mi * 16 + fg * 4;
        #pragma unroll
        for (int ni = 0; ni < NI; ++ni) {
            int col = col0 + wn + ni * 16 + fr;
            float bv = bias[col];
            #pragma unroll
            for (int r = 0; r < 4; ++r) {
                float v = acc[mi][ni][r] + bv;
                int rr = rowb + r;
                if (EPI == 0) {
                    int part = col >> 10, c = col & 1023;
                    int h = c >> 6, d = c & 63;
                    int b = rr >> 11, t = rr & 2047;
                    if (part == 0) v *= 0.18033688011112042f;   // fold log2(e)/sqrt(D) into Q
                    size_t idx = (size_t)part * BHTD_ + ((size_t)(b * H_ + h) * T_ + t) * D_ + d;
                    out_bf16[idx] = f32_bf16(v);
                } else {
                    out_f32[(size_t)rr * N + col] = v;
                }
            }
        }
    }
}

// ---------------- causal flash attention v13 (round-16 proven, unchanged) ----------------
__global__ __launch_bounds__(256) void attn_kernel(
    const unsigned short* __restrict__ qg,
    const unsigned short* __restrict__ kg,
    const unsigned short* __restrict__ vtg,  // [bh][D][T]
    unsigned short* __restrict__ y)
{
    const int id = blockIdx.x;
    const int xcd = id & 7, loc = id >> 3;
    const int bh = xcd * 4 + (loc & 3);      // 4 heads per XCD -> K/V L2-resident
    const int iq0 = loc >> 2;                // [0,16)
    const int iq = (iq0 < 8) ? iq0 : 23 - iq0;
    const int chlo = iq, chhi = 31 - iq;     // 64-row q chunks
    const int b = bh >> 4, h = bh & 15;
    const int tid = threadIdx.x, wid = tid >> 6, lane = tid & 63;
    const int fr = lane & 15, fg = lane >> 4;

    const unsigned short* qp = qg + (size_t)bh * (T_ * D_);
    const char* kpB = (const char*)(kg + (size_t)bh * (T_ * D_));
    const char* vpB = (const char*)(vtg + (size_t)bh * (D_ * T_));

    __shared__ __align__(16) char Ks[2][8192];       // [kv][128B], XOR-swizzled
    __shared__ __align__(16) char Vs[2][8192];       // [d][128B], XOR-swizzled
    __shared__ __align__(16) char Ps[4][32 * 128];   // per-wave P: [stream*16+row][kv]
    char* Pw = Ps[wid];

    const int rhi = chhi * 64 + wid * 16;
    const int rlo = chlo * 64 + wid * 16;

    bf16x8 qhi[2], qlo[2];
    #pragma unroll
    for (int kd = 0; kd < 2; ++kd) {
        qhi[kd] = *(const bf16x8*)(qp + (size_t)(rhi + fr) * D_ + kd * 32 + fg * 8);
        qlo[kd] = *(const bf16x8*)(qp + (size_t)(rlo + fr) * D_ + kd * 32 + fg * 8);
    }

    f32x4 oHi[4], oLo[4];
    float lHi = 0.f, lLo = 0.f;
    #pragma unroll
    for (int n = 0; n < 4; ++n) {
        oHi[n] = (f32x4){0.f, 0.f, 0.f, 0.f};
        oLo[n] = (f32x4){0.f, 0.f, 0.f, 0.f};
    }

    const int ntk  = chhi + 1;
    const int ntlo = chlo + 1;

    const int srow8 = lane >> 3;
    const int scol  = (lane & 7) * 16;
    const int ssw   = srow8 << 4;

    auto stage = [&](int buf, int kv0) {
        #pragma unroll
        for (int bc = 0; bc < 2; ++bc) {
            const int rbase = wid * 16 + bc * 8;
            __builtin_amdgcn_global_load_lds(
                (const AS1 void*)(kpB + (size_t)(kv0 + rbase + srow8) * 128 + (scol ^ ssw)),
                (AS3 void*)(Ks[buf] + rbase * 128), 16, 0, 0);
            __builtin_amdgcn_global_load_lds(
                (const AS1 void*)(vpB + (size_t)(rbase + srow8) * 4096 + (size_t)kv0 * 2 + (scol ^ ssw)),
                (AS3 void*)(Vs[buf] + rbase * 128), 16, 0, 0);
        }
    };

    stage(0, 0);
    __syncthreads();

    const unsigned lsw = (unsigned)((fr & 7) << 4);
    int cur = 0;
    for (int t = 0; t < ntk; ++t) {
        const int kv0 = t * 64;
        if (t + 1 < ntk) stage(cur ^ 1, kv0 + 64);

        const char* Kb = Ks[cur];
        const char* Vb = Vs[cur];
        const bool lo_act = (t < ntlo);

        f32x4 sh[4], sl[4];
        #pragma unroll
        for (int n = 0; n < 4; ++n) {
            sh[n] = (f32x4){0.f, 0.f, 0.f, 0.f};
            sl[n] = (f32x4){0.f, 0.f, 0.f, 0.f};
        }
        __builtin_amdgcn_s_setprio(1);
        #pragma unroll
        for (int kd = 0; kd < 2; ++kd)
            #pragma unroll
            for (int n = 0; n < 4; ++n) {
                bf16x8 kf = *(const bf16x8*)(Kb + (n * 16 + fr) * 128 +
                                             (((unsigned)(kd * 64 + fg * 16)) ^ lsw));
                sh[n] = __builtin_amdgcn_mfma_f32_16x16x32_bf16(kf, qhi[kd], sh[n], 0, 0, 0);
                if (lo_act)
                    sl[n] = __builtin_amdgcn_mfma_f32_16x16x32_bf16(kf, qlo[kd], sl[n], 0, 0, 0);
            }
        __builtin_amdgcn_s_setprio(0);

        bf16x8 vf[4][2];
        #pragma unroll
        for (int nd = 0; nd < 4; ++nd)
            #pragma unroll
            for (int kk = 0; kk < 2; ++kk)
                vf[nd][kk] = *(const bf16x8*)(Vb + (nd * 16 + fr) * 128 +
                                              (((unsigned)(kk * 64 + fg * 16)) ^ lsw));

        {
            const bool masked = (t == chhi);
            const int qrow = rhi + fr;
            const unsigned prow = (unsigned)fr * 128;
            #pragma unroll
            for (int n = 0; n < 4; ++n) {
                float x0 = sh[n][0], x1 = sh[n][1], x2 = sh[n][2], x3 = sh[n][3];
                if (masked) {
                    const int kvb = kv0 + n * 16 + fg * 4;
                    if (kvb     > qrow) x0 = -1e30f;
                    if (kvb + 1 > qrow) x1 = -1e30f;
                    if (kvb + 2 > qrow) x2 = -1e30f;
                    if (kvb + 3 > qrow) x3 = -1e30f;
                }
                const float p0 = __builtin_amdgcn_exp2f(x0);
                const float p1 = __builtin_amdgcn_exp2f(x1);
                const float p2 = __builtin_amdgcn_exp2f(x2);
                const float p3 = __builtin_amdgcn_exp2f(x3);
                lHi += (p0 + p1) + (p2 + p3);
                bf16x4 pk4 = {(__bf16)p0, (__bf16)p1, (__bf16)p2, (__bf16)p3};
                *(uint2*)(Pw + ((prow + (unsigned)(n * 32 + fg * 8)) ^ lsw)) =
                    __builtin_bit_cast(uint2, pk4);
            }
        }
        {
            const unsigned prow = (unsigned)fr * 128;
            __builtin_amdgcn_s_setprio(1);
            #pragma unroll
            for (int kk = 0; kk < 2; ++kk) {
                bf16x8 pb = *(const bf16x8*)(Pw + ((prow + (unsigned)(kk * 64 + fg * 16)) ^ lsw));
                #pragma unroll
                for (int nd = 0; nd < 4; ++nd)
                    oHi[nd] = __builtin_amdgcn_mfma_f32_16x16x32_bf16(vf[nd][kk], pb, oHi[nd], 0, 0, 0);
            }
            __builtin_amdgcn_s_setprio(0);
        }
        if (lo_act) {
            const bool masked = (t == chlo);
            const int qrow = rlo + fr;
            const unsigned prow = (unsigned)(16 + fr) * 128;
            #pragma unroll
            for (int n = 0; n < 4; ++n) {
                float x0 = sl[n][0], x1 = sl[n][1], x2 = sl[n][2], x3 = sl[n][3];
                if (masked) {
                    const int kvb = kv0 + n * 16 + fg * 4;
                    if (kvb     > qrow) x0 = -1e30f;
                    if (kvb + 1 > qrow) x1 = -1e30f;
                    if (kvb + 2 > qrow) x2 = -1e30f;
                    if (kvb + 3 > qrow) x3 = -1e30f;
                }
                const float p0 = __builtin_amdgcn_exp2f(x0);
                const float p1 = __builtin_amdgcn_exp2f(x1);
                const float p2 = __builtin_amdgcn_exp2f(x2);
                const float p3 = __builtin_amdgcn_exp2f(x3);
                lLo += (p0 + p1) + (p2 + p3);
                bf16x4 pk4 = {(__bf16)p0, (__bf16)p1, (__bf16)p2, (__bf16)p3};
                *(uint2*)(Pw + ((prow + (unsigned)(n * 32 + fg * 8)) ^ lsw)) =
                    __builtin_bit_cast(uint2, pk4);
            }
            __builtin_amdgcn_s_setprio(1);
            #pragma unroll
            for (int kk = 0; kk < 2; ++kk) {
                bf16x8 pb = *(const bf16x8*)(Pw + ((prow + (unsigned)(kk * 64 + fg * 16)) ^ lsw));
                #pragma unroll
                for (int nd = 0; nd < 4; ++nd)
                    oLo[nd] = __builtin_amdgcn_mfma_f32_16x16x32_bf16(vf[nd][kk], pb, oLo[nd], 0, 0, 0);
            }
            __builtin_amdgcn_s_setprio(0);
        }

        __syncthreads();
        cur ^= 1;
    }

    #pragma unroll
    for (int s = 0; s < 2; ++s) {
        float rs = s ? lLo : lHi;
        rs += __shfl_xor(rs, 16);
        rs += __shfl_xor(rs, 32);
        const float inv = 1.f / rs;
        const int trow = (s ? rlo : rhi) + fr;
        f32x4* oT = s ? oLo : oHi;
        #pragma unroll
        for (int nd = 0; nd < 4; ++nd) {
            bf16x4 ov = {(__bf16)(oT[nd][0] * inv), (__bf16)(oT[nd][1] * inv),
                         (__bf16)(oT[nd][2] * inv), (__bf16)(oT[nd][3] * inv)};
            *(uint2*)(y + ((size_t)b * T_ + trow) * C_ + h * 64 + nd * 16 + fg * 4) =
                __builtin_bit_cast(uint2, ov);
        }
    }
}

// ---------------- launch ----------------
extern "C" void kernel_launch(void* const* d_in, const int* in_sizes, int n_in,
                              void* d_out, int out_size, void* d_ws, size_t ws_size,
                              hipStream_t stream) {
    const float* x     = (const float*)d_in[0];
    const float* Wqkv  = (const float*)d_in[1];
    const float* bqkv  = (const float*)d_in[2];
    const float* Wproj = (const float*)d_in[3];
    const float* bproj = (const float*)d_in[4];
    float* out = (float*)d_out;

    char* ws = (char*)d_ws;
    unsigned short* x_bf    = (unsigned short*)(ws);                 //  8 MB
    unsigned short* wqkv_t  = (unsigned short*)(ws + 8388608);       //  6 MB
    unsigned short* wproj_t = (unsigned short*)(ws + 14680064);      //  2 MB
    unsigned short* qkv     = (unsigned short*)(ws + 16777216);      // 24 MB
    unsigned short* ybuf    = (unsigned short*)(ws + 41943040);      //  8 MB

    prep_kernel<<<dim3(8192), 256, 0, stream>>>(x, x_bf, Wqkv, wqkv_t, Wproj, wproj_t);

    gemm_bt<0, 64><<<dim3(M_ / 128, 3072 / 64), 256, 0, stream>>>(
        x_bf, wqkv_t, bqkv, qkv, nullptr, M_, 3072, 1024);

    attn_kernel<<<dim3(512), 256, 0, stream>>>(
        qkv, qkv + (size_t)BHTD_, qkv + 2 * (size_t)BHTD_, ybuf);

    gemm_bt<1, 64><<<dim3(M_ / 128, 1024 / 64), 256, 0, stream>>>(
        ybuf, wproj_t, bproj, nullptr, out, M_, 1024, 1024);
}